// Round 4
// baseline (256.690 us; speedup 1.0000x reference)
//
#include <hip/hip_runtime.h>

// Fused: z = x @ W^T + b_lin; y = swish(z) + b_ex; GroupNorm(32 groups) * gn_w + gn_b
// x: [8192, 2048] f32, W: [4096, 2048] f32, out: [8192, 4096] f32
// Round 4: R3's 4-phase/K-tile counted-vmcnt pipeline + in-region LDS XOR
// swizzle SW(row)=((row^(row>>2))&3) -> 2-way (free) bank access, + 8x8-patch
// XCD block swizzle.

typedef __attribute__((ext_vector_type(8))) short short8;
typedef __attribute__((ext_vector_type(4))) float f32x4;

#define M_DIM 8192
#define N_DIM 4096
#define K_DIM 2048
#define BM 256
#define BN 256
#define BK 64
#define NT (K_DIM / BK)  // 32

// ---------------- f32 -> bf16 (RNE) convert, 8 elems/thread ----------------
__global__ void f32_to_bf16_k(const float* __restrict__ in, ushort* __restrict__ out, int n8) {
    int i = blockIdx.x * blockDim.x + threadIdx.x;
    if (i >= n8) return;
    const float4* p = (const float4*)in + 2 * (size_t)i;
    float4 a = p[0], b = p[1];
    float v[8] = {a.x, a.y, a.z, a.w, b.x, b.y, b.z, b.w};
    ushort rr[8];
#pragma unroll
    for (int j = 0; j < 8; ++j) {
        unsigned u = __float_as_uint(v[j]);
        rr[j] = (ushort)((u + 0x7fffu + ((u >> 16) & 1u)) >> 16);  // RNE
    }
    uint4 o;
    o.x = (unsigned)rr[0] | ((unsigned)rr[1] << 16);
    o.y = (unsigned)rr[2] | ((unsigned)rr[3] << 16);
    o.z = (unsigned)rr[4] | ((unsigned)rr[5] << 16);
    o.w = (unsigned)rr[6] | ((unsigned)rr[7] << 16);
    ((uint4*)out)[i] = o;
}

// LDS per K-tile buffer (32768 ushorts = 64 KiB), regions (ushort offsets):
//   A_k0 [0,8192)  A_k1 [8192,16384)  B_k0 [16384,24576)  B_k1 [24576,32768)
// region layout: [256 rows][32 ushorts], with 16B-slot swizzle
//   slot(row, h) = h ^ SW(row),  SW(row) = ((row ^ (row>>2)) & 3)
// -> quarter-wave b128 reads land 2 lanes/bank-group = 2-way = free.
// Staging writes LDS linearly (global_load_lds), source col pre-swizzled.

#define BAR() __builtin_amdgcn_s_barrier()
#define LGKM0() do { asm volatile("s_waitcnt lgkmcnt(0)" ::: "memory"); __builtin_amdgcn_sched_barrier(0); } while (0)
#define VMC(n_) do { asm volatile("s_waitcnt vmcnt(" #n_ ")" ::: "memory"); __builtin_amdgcn_sched_barrier(0); } while (0)

__global__ __launch_bounds__(512, 2) void gemm_swish_gn(
    const ushort* __restrict__ xb, const ushort* __restrict__ wb,
    const float* __restrict__ bias_lin, const float* __restrict__ bias_extra,
    const float* __restrict__ gn_w, const float* __restrict__ gn_b,
    float* __restrict__ out)
{
    extern __shared__ __align__(16) ushort lds[];  // 2 x 32768 ushorts

    const int t = threadIdx.x;
    const int w = t >> 6;
    const int l = t & 63;
    const int wm = w >> 2;   // 0..1
    const int wn = w & 3;    // 0..3
    const int h = l >> 4;    // 0..3
    const int r = l & 15;    // 0..15

    // T1: 8x8-patch XCD swizzle (512 blocks = 8 XCD-patches of 8x8 tiles)
    const int bid = blockIdx.x;
    const int xcd = bid & 7;
    const int g = bid >> 3;                  // 0..63 within patch
    const int brow = (xcd & 3) * 8 + (g & 7);   // 0..31
    const int bcol = (xcd >> 2) * 8 + (g >> 3); // 0..15

    // ---- staging source pointers (source col pre-swizzled; K advances by 32)
    const int swT = ((t >> 2) ^ (t >> 4)) & 3;   // SW(row=t>>2), invariant for row+128
    const int scol = ((t & 3) ^ swT) * 8;        // swizzled source col (ushorts)
    const ushort* pA0 = xb + (size_t)(brow * BM + (t >> 2)) * K_DIM + scol;
    const ushort* pA1 = pA0 + (size_t)128 * K_DIM;
    const ushort* pB0 = wb + (size_t)(bcol * BN + (t >> 2)) * K_DIM + scol;
    const ushort* pB1 = pB0 + (size_t)128 * K_DIM;
    const int dst0 = t * 8;  // linear LDS dst (ushorts) within a 4096-ushort round

#define STAGE_A(slotU) do {                                                   \
    __builtin_amdgcn_global_load_lds(                                         \
        (const __attribute__((address_space(1))) void*)pA0,                   \
        (__attribute__((address_space(3))) void*)&lds[(slotU) + dst0], 16, 0, 0); \
    __builtin_amdgcn_global_load_lds(                                         \
        (const __attribute__((address_space(1))) void*)pA1,                   \
        (__attribute__((address_space(3))) void*)&lds[(slotU) + 4096 + dst0], 16, 0, 0); \
    pA0 += 32; pA1 += 32; } while (0)

#define STAGE_B(slotU) do {                                                   \
    __builtin_amdgcn_global_load_lds(                                         \
        (const __attribute__((address_space(1))) void*)pB0,                   \
        (__attribute__((address_space(3))) void*)&lds[(slotU) + dst0], 16, 0, 0); \
    __builtin_amdgcn_global_load_lds(                                         \
        (const __attribute__((address_space(1))) void*)pB1,                   \
        (__attribute__((address_space(3))) void*)&lds[(slotU) + 4096 + dst0], 16, 0, 0); \
    pB0 += 32; pB1 += 32; } while (0)

    // frag read base offsets (ushorts), loop-invariant per thread (SW(r) folds in)
    const int swR = ((r ^ (r >> 2)) & 3);
    const int aIdx = (wm * 128 + r) * 32 + (h ^ swR) * 8;  // + m*512 (+ region)
    const int bIdx = (wn * 64 + r) * 32 + (h ^ swR) * 8;   // + n*512 (+ region)

    f32x4 acc[8][4];
#pragma unroll
    for (int m = 0; m < 8; ++m)
#pragma unroll
        for (int n = 0; n < 4; ++n)
            acc[m][n] = f32x4{0.f, 0.f, 0.f, 0.f};

    // ---- prologue: 6 half-tiles (12 loads), then gate first K-tile
    STAGE_A(0);              // t0.A_k0
    STAGE_B(16384);          // t0.B_k0
    STAGE_A(8192);           // t0.A_k1
    STAGE_B(24576);          // t0.B_k1
    STAGE_A(32768 + 0);      // t1.A_k0
    STAGE_B(32768 + 16384);  // t1.B_k0
    VMC(8);                  // t0.A_k0, t0.B_k0 landed
    BAR();

    short8 aF[8], bF[4];

#define DO_TILE(P, tt)                                                              \
  {                                                                                 \
    /* ---- ph1 (kk=0, n0-1) ---- */                                                \
    _Pragma("unroll") for (int m = 0; m < 8; ++m)                                   \
        aF[m] = *(const short8*)&lds[(P) * 32768 + aIdx + m * 512];                 \
    bF[0] = *(const short8*)&lds[(P) * 32768 + 16384 + bIdx];                       \
    bF[1] = *(const short8*)&lds[(P) * 32768 + 16384 + bIdx + 512];                 \
    if ((tt) != NT - 1) STAGE_A(((P) ^ 1) * 32768 + 8192);                          \
    BAR(); LGKM0();                                                                 \
    __builtin_amdgcn_s_setprio(1);                                                  \
    _Pragma("unroll") for (int m = 0; m < 8; ++m) {                                 \
        acc[m][0] = __builtin_amdgcn_mfma_f32_16x16x32_bf16(aF[m], bF[0], acc[m][0], 0, 0, 0); \
        acc[m][1] = __builtin_amdgcn_mfma_f32_16x16x32_bf16(aF[m], bF[1], acc[m][1], 0, 0, 0); \
    }                                                                               \
    __builtin_amdgcn_s_setprio(0);                                                  \
    BAR();                                                                          \
    /* ---- ph2 (kk=0, n2-3) ---- */                                                \
    bF[2] = *(const short8*)&lds[(P) * 32768 + 16384 + bIdx + 1024];                \
    bF[3] = *(const short8*)&lds[(P) * 32768 + 16384 + bIdx + 1536];                \
    if ((tt) != NT - 1) STAGE_B(((P) ^ 1) * 32768 + 24576);                         \
    BAR(); LGKM0();                                                                 \
    __builtin_amdgcn_s_setprio(1);                                                  \
    _Pragma("unroll") for (int m = 0; m < 8; ++m) {                                 \
        acc[m][2] = __builtin_amdgcn_mfma_f32_16x16x32_bf16(aF[m], bF[2], acc[m][2], 0, 0, 0); \
        acc[m][3] = __builtin_amdgcn_mfma_f32_16x16x32_bf16(aF[m], bF[3], acc[m][3], 0, 0, 0); \
    }                                                                               \
    __builtin_amdgcn_s_setprio(0);                                                  \
    if ((tt) == NT - 1) { VMC(0); } else { VMC(8); }                                \
    BAR();                                                                          \
    /* ---- ph3 (kk=1, n0-1) ---- */                                                \
    _Pragma("unroll") for (int m = 0; m < 8; ++m)                                   \
        aF[m] = *(const short8*)&lds[(P) * 32768 + 8192 + aIdx + m * 512];          \
    bF[0] = *(const short8*)&lds[(P) * 32768 + 24576 + bIdx];                       \
    bF[1] = *(const short8*)&lds[(P) * 32768 + 24576 + bIdx + 512];                 \
    if ((tt) < NT - 2) STAGE_A((P) * 32768 + 0);                                    \
    BAR(); LGKM0();                                                                 \
    __builtin_amdgcn_s_setprio(1);                                                  \
    _Pragma("unroll") for (int m = 0; m < 8; ++m) {                                 \
        acc[m][0] = __builtin_amdgcn_mfma_f32_16x16x32_bf16(aF[m], bF[0], acc[m][0], 0, 0, 0); \
        acc[m][1] = __builtin_amdgcn_mfma_f32_16x16x32_bf16(aF[m], bF[1], acc[m][1], 0, 0, 0); \
    }                                                                               \
    __builtin_amdgcn_s_setprio(0);                                                  \
    BAR();                                                                          \
    /* ---- ph4 (kk=1, n2-3) ---- */                                                \
    bF[2] = *(const short8*)&lds[(P) * 32768 + 24576 + bIdx + 1024];                \
    bF[3] = *(const short8*)&lds[(P) * 32768 + 24576 + bIdx + 1536];                \
    if ((tt) < NT - 2) STAGE_B((P) * 32768 + 16384);                                \
    BAR(); LGKM0();                                                                 \
    __builtin_amdgcn_s_setprio(1);                                                  \
    _Pragma("unroll") for (int m = 0; m < 8; ++m) {                                 \
        acc[m][2] = __builtin_amdgcn_mfma_f32_16x16x32_bf16(aF[m], bF[2], acc[m][2], 0, 0, 0); \
        acc[m][3] = __builtin_amdgcn_mfma_f32_16x16x32_bf16(aF[m], bF[3], acc[m][3], 0, 0, 0); \
    }                                                                               \
    __builtin_amdgcn_s_setprio(0);                                                  \
    if ((tt) == NT - 2) { VMC(4); } else if ((tt) < NT - 2) { VMC(8); }             \
    BAR();                                                                          \
  }

#pragma unroll 1
    for (int tp = 0; tp < NT; tp += 2) {
        DO_TILE(0, tp);
        DO_TILE(1, tp + 1);
    }

    // ---- epilogue: bias + swish + extra bias, GroupNorm per 128-col group ----
    const int colbase = bcol * BN + wn * 64;
    float bl[4], be[4], gwv[4], gbv[4];
#pragma unroll
    for (int n = 0; n < 4; ++n) {
        int col = colbase + n * 16 + r;
        bl[n] = bias_lin[col];
        be[n] = bias_extra[col];
        gwv[n] = gn_w[col];
        gbv[n] = gn_b[col];
    }

    float s1[8][4], s2[8][4];
#pragma unroll
    for (int m = 0; m < 8; ++m)
#pragma unroll
        for (int j = 0; j < 4; ++j) { s1[m][j] = 0.f; s2[m][j] = 0.f; }

#pragma unroll
    for (int m = 0; m < 8; ++m)
#pragma unroll
        for (int n = 0; n < 4; ++n)
#pragma unroll
            for (int j = 0; j < 4; ++j) {
                float z = acc[m][n][j] + bl[n];
                float sw = z / (1.f + __expf(-z)) + be[n];
                acc[m][n][j] = sw;
                s1[m][j] += sw;
                s2[m][j] += sw * sw;
            }

#pragma unroll
    for (int mask = 1; mask < 16; mask <<= 1) {
#pragma unroll
        for (int m = 0; m < 8; ++m)
#pragma unroll
            for (int j = 0; j < 4; ++j) {
                s1[m][j] += __shfl_xor(s1[m][j], mask, 16);
                s2[m][j] += __shfl_xor(s2[m][j], mask, 16);
            }
    }

    float* sred = (float*)lds;  // [2 stat][2 group-half][2 wave-pair][256 rows]
    const int gh = wn >> 1;
    const int p = wn & 1;
    if (r == 0) {
#pragma unroll
        for (int m = 0; m < 8; ++m)
#pragma unroll
            for (int j = 0; j < 4; ++j) {
                int row = wm * 128 + m * 16 + h * 4 + j;
                sred[((0 * 2 + gh) * 2 + p) * 256 + row] = s1[m][j];
                sred[((1 * 2 + gh) * 2 + p) * 256 + row] = s2[m][j];
            }
    }
    __syncthreads();

    const size_t orow0 = (size_t)brow * BM;
#pragma unroll
    for (int m = 0; m < 8; ++m)
#pragma unroll
        for (int j = 0; j < 4; ++j) {
            int row = wm * 128 + m * 16 + h * 4 + j;
            float mu = (sred[((0 * 2 + gh) * 2 + 0) * 256 + row] +
                        sred[((0 * 2 + gh) * 2 + 1) * 256 + row]) * (1.f / 128.f);
            float ex2 = (sred[((1 * 2 + gh) * 2 + 0) * 256 + row] +
                         sred[((1 * 2 + gh) * 2 + 1) * 256 + row]) * (1.f / 128.f);
            float var = ex2 - mu * mu;
            float rs = rsqrtf(var + 1e-5f);
            float* orow = out + (orow0 + row) * N_DIM;
#pragma unroll
            for (int n = 0; n < 4; ++n) {
                int col = colbase + n * 16 + r;
                orow[col] = (acc[m][n][j] - mu) * rs * gwv[n] + gbv[n];
            }
        }
}

extern "C" void kernel_launch(void* const* d_in, const int* in_sizes, int n_in,
                              void* d_out, int out_size, void* d_ws, size_t ws_size,
                              hipStream_t stream) {
    const float* x        = (const float*)d_in[0];
    const float* weight   = (const float*)d_in[1];
    const float* bias_lin = (const float*)d_in[2];
    const float* bias_ex  = (const float*)d_in[3];
    const float* gn_w     = (const float*)d_in[4];
    const float* gn_b     = (const float*)d_in[5];
    float* out = (float*)d_out;

    ushort* xb = (ushort*)d_ws;                     // 32 MiB bf16
    ushort* wb = xb + (size_t)M_DIM * K_DIM;        // 16 MiB bf16

    {
        int n8 = (M_DIM * K_DIM) / 8;
        f32_to_bf16_k<<<n8 / 256, 256, 0, stream>>>(x, xb, n8);
    }
    {
        int n8 = (N_DIM * K_DIM) / 8;
        f32_to_bf16_k<<<n8 / 256, 256, 0, stream>>>(weight, wb, n8);
    }

    (void)hipFuncSetAttribute((const void*)gemm_swish_gn,
                              hipFuncAttributeMaxDynamicSharedMemorySize, 131072);

    dim3 grid((M_DIM / BM) * (N_DIM / BN));  // 512 blocks
    gemm_swish_gn<<<grid, 512, 131072, stream>>>(xb, wb, bias_lin, bias_ex, gn_w, gn_b, out);
}

// Round 5
// 191.149 us; speedup vs baseline: 1.3429x; 1.3429x over previous
//
#include <hip/hip_runtime.h>

// Fused: z = x @ W^T + b_lin; y = swish(z) + b_ex; GroupNorm(32 groups) * gn_w + gn_b
// x: [8192, 2048] f32, W: [4096, 2048] f32, out: [8192, 4096] f32
// Round 5: 4-phase/K-tile counted-vmcnt pipeline on R2's PROVEN 0-conflict LDS
// geometry (128B rows, (r&7)<<4 XOR, pre-swizzled source). Chunks = row-halves.

typedef __attribute__((ext_vector_type(8))) short short8;
typedef __attribute__((ext_vector_type(4))) float f32x4;

#define M_DIM 8192
#define N_DIM 4096
#define K_DIM 2048
#define BM 256
#define BN 256
#define BK 64
#define NT (K_DIM / BK)  // 32

#define AS1 __attribute__((address_space(1)))
#define AS3 __attribute__((address_space(3)))

// ---------------- f32 -> bf16 (RNE) convert, 8 elems/thread ----------------
__global__ void f32_to_bf16_k(const float* __restrict__ in, ushort* __restrict__ out, int n8) {
    int i = blockIdx.x * blockDim.x + threadIdx.x;
    if (i >= n8) return;
    const float4* p = (const float4*)in + 2 * (size_t)i;
    float4 a = p[0], b = p[1];
    float v[8] = {a.x, a.y, a.z, a.w, b.x, b.y, b.z, b.w};
    ushort rr[8];
#pragma unroll
    for (int j = 0; j < 8; ++j) {
        unsigned u = __float_as_uint(v[j]);
        rr[j] = (ushort)((u + 0x7fffu + ((u >> 16) & 1u)) >> 16);  // RNE
    }
    uint4 o;
    o.x = (unsigned)rr[0] | ((unsigned)rr[1] << 16);
    o.y = (unsigned)rr[2] | ((unsigned)rr[3] << 16);
    o.z = (unsigned)rr[4] | ((unsigned)rr[5] << 16);
    o.w = (unsigned)rr[6] | ((unsigned)rr[7] << 16);
    ((uint4*)out)[i] = o;
}

// LDS: 2 buffers x 64KB. Buffer (ushort offsets): A region [0,16384): 256 rows
// x 64 sh (128B rows, K-halves kk0|kk1 within row); B region [16384,32768).
// Read swizzle: 16B-slot index = (kk*4 + h) ^ (r&7)  [R2-proven 0-conflict].
// Staged linearly; global SOURCE col pre-swizzled by the same involution.

#define BAR() __builtin_amdgcn_s_barrier()
#define LGKM0() do { asm volatile("s_waitcnt lgkmcnt(0)" ::: "memory"); __builtin_amdgcn_sched_barrier(0); } while (0)
#define VMC(n_) do { asm volatile("s_waitcnt vmcnt(" #n_ ")" ::: "memory"); __builtin_amdgcn_sched_barrier(0); } while (0)

__global__ __launch_bounds__(512, 2) void gemm_swish_gn(
    const ushort* __restrict__ xb, const ushort* __restrict__ wb,
    const float* __restrict__ bias_lin, const float* __restrict__ bias_extra,
    const float* __restrict__ gn_w, const float* __restrict__ gn_b,
    float* __restrict__ out)
{
    extern __shared__ __align__(16) ushort lds[];  // 2 x 32768 ushorts

    const int t = threadIdx.x;
    const int w = t >> 6;
    const int l = t & 63;
    const int wm = w >> 2;   // 0..1
    const int wn = w & 3;    // 0..3
    const int h = l >> 4;    // 0..3
    const int r = l & 15;    // 0..15

    // T1: R2's simple XCD swizzle (512 blocks, bijective)
    const int bid = blockIdx.x;
    const int id = (bid & 7) * 64 + (bid >> 3);
    const int brow = id & 31;   // M tile
    const int bcol = id >> 5;   // N tile (= 2 GroupNorm groups)

    // ---- staging: thread t covers row s=t>>3 (per round), 16B slot t&7.
    // Source col pre-swizzled by slot ^= (row&7) so linear LDS + swizzled read match.
    const int s = t >> 3;
    const int scol = (((t & 7) ^ (s & 7)) << 3);            // ushorts
    const ushort* pA = xb + (size_t)(brow * BM + s) * K_DIM + scol;
    const int rB = (s & 31) + ((s >> 5) << 6);              // B scattered row base
    const ushort* pB = wb + (size_t)(bcol * BN + rB) * K_DIM + scol;
    const int dstA = t * 8;                                 // = s*64 + (t&7)*8
    const int dstB = rB * 64 + ((t & 7) << 3);

    // chunk rounds: A-lo: ROFF {0,128}; A-hi: {64,192}; B-lo: {0,128}; B-hi: {32,160}
#define STG_A(P, ROFF) __builtin_amdgcn_global_load_lds(                         \
        (const AS1 void*)(pA + (size_t)(ROFF) * K_DIM),                          \
        (AS3 void*)&lds[(P) * 32768 + (ROFF) * 64 + dstA], 16, 0, 0)
#define STG_B(P, ROFF) __builtin_amdgcn_global_load_lds(                         \
        (const AS1 void*)(pB + (size_t)(ROFF) * K_DIM),                          \
        (AS3 void*)&lds[(P) * 32768 + 16384 + (ROFF) * 64 + dstB], 16, 0, 0)

    // ---- fragment read offsets (ushorts): row*64 + ((kk*32 + h*8) ^ (r&7)*8)
    const int xr8 = (r & 7) << 3;
    const int aOff0 = (wm * 128 + r) * 64 + ((h << 3) ^ xr8);           // kk0
    const int aOff1 = aOff0 ^ 32;                                       // kk1
    const int bOff0 = 16384 + (wn * 64 + r) * 64 + ((h << 3) ^ xr8);
    const int bOff1 = bOff0 ^ 32;

    f32x4 acc[8][4];
#pragma unroll
    for (int m = 0; m < 8; ++m)
#pragma unroll
        for (int n = 0; n < 4; ++n)
            acc[m][n] = f32x4{0.f, 0.f, 0.f, 0.f};

    // ---- prologue: full tile 0 (8 loads), keep B-hi in flight
    STG_A(0, 0); STG_A(0, 128);   // A-lo
    STG_A(0, 64); STG_A(0, 192);  // A-hi
    STG_B(0, 0); STG_B(0, 128);   // B-lo
    STG_B(0, 32); STG_B(0, 160);  // B-hi
    pA += BK; pB += BK;
    VMC(2);
    BAR();

    short8 aF[4][2], bF[4][2];

#define MFMA(mm, nn, kk, ai) \
    acc[mm][nn] = __builtin_amdgcn_mfma_f32_16x16x32_bf16(aF[ai][kk], bF[nn][kk], acc[mm][nn], 0, 0, 0)

#define DO_TILE(P, tt)                                                              \
  {                                                                                 \
    /* ---- ph1: m0-3 x n0-1 ---- */                                                \
    _Pragma("unroll") for (int m = 0; m < 4; ++m) {                                 \
        aF[m][0] = *(const short8*)&lds[(P) * 32768 + aOff0 + m * 1024];            \
        aF[m][1] = *(const short8*)&lds[(P) * 32768 + aOff1 + m * 1024];            \
    }                                                                               \
    _Pragma("unroll") for (int n = 0; n < 2; ++n) {                                 \
        bF[n][0] = *(const short8*)&lds[(P) * 32768 + bOff0 + n * 1024];            \
        bF[n][1] = *(const short8*)&lds[(P) * 32768 + bOff1 + n * 1024];            \
    }                                                                               \
    if ((tt) != NT - 1) { STG_A(P ^ 1, 0); STG_A(P ^ 1, 128); }                     \
    BAR(); LGKM0();                                                                 \
    __builtin_amdgcn_s_setprio(1);                                                  \
    _Pragma("unroll") for (int m = 0; m < 4; ++m)                                   \
        _Pragma("unroll") for (int n = 0; n < 2; ++n) {                             \
            MFMA(m, n, 0, m); MFMA(m, n, 1, m);                                     \
        }                                                                           \
    __builtin_amdgcn_s_setprio(0);                                                  \
    if ((tt) == NT - 1) { VMC(0); } else { VMC(2); }                                \
    BAR();                                                                          \
    /* ---- ph2: m0-3 x n2-3 ---- */                                                \
    _Pragma("unroll") for (int n = 2; n < 4; ++n) {                                 \
        bF[n][0] = *(const short8*)&lds[(P) * 32768 + bOff0 + n * 1024];            \
        bF[n][1] = *(const short8*)&lds[(P) * 32768 + bOff1 + n * 1024];            \
    }                                                                               \
    if ((tt) != NT - 1) { STG_A(P ^ 1, 64); STG_A(P ^ 1, 192); }                    \
    BAR(); LGKM0();                                                                 \
    __builtin_amdgcn_s_setprio(1);                                                  \
    _Pragma("unroll") for (int m = 0; m < 4; ++m)                                   \
        _Pragma("unroll") for (int n = 2; n < 4; ++n) {                             \
            MFMA(m, n, 0, m); MFMA(m, n, 1, m);                                     \
        }                                                                           \
    __builtin_amdgcn_s_setprio(0);                                                  \
    BAR();                                                                          \
    /* ---- ph3: m4-7 x n0-1 (aF overwritten) ---- */                               \
    _Pragma("unroll") for (int m = 4; m < 8; ++m) {                                 \
        aF[m - 4][0] = *(const short8*)&lds[(P) * 32768 + aOff0 + m * 1024];        \
        aF[m - 4][1] = *(const short8*)&lds[(P) * 32768 + aOff1 + m * 1024];        \
    }                                                                               \
    if ((tt) != NT - 1) { STG_B(P ^ 1, 0); STG_B(P ^ 1, 128); }                     \
    BAR(); LGKM0();                                                                 \
    __builtin_amdgcn_s_setprio(1);                                                  \
    _Pragma("unroll") for (int m = 4; m < 8; ++m)                                   \
        _Pragma("unroll") for (int n = 0; n < 2; ++n) {                             \
            MFMA(m, n, 0, m - 4); MFMA(m, n, 1, m - 4);                             \
        }                                                                           \
    __builtin_amdgcn_s_setprio(0);                                                  \
    BAR();                                                                          \
    /* ---- ph4: m4-7 x n2-3 (register-only) ---- */                                \
    if ((tt) != NT - 1) { STG_B(P ^ 1, 32); STG_B(P ^ 1, 160); pA += BK; pB += BK; } \
    BAR(); LGKM0();                                                                 \
    __builtin_amdgcn_s_setprio(1);                                                  \
    _Pragma("unroll") for (int m = 4; m < 8; ++m)                                   \
        _Pragma("unroll") for (int n = 2; n < 4; ++n) {                             \
            MFMA(m, n, 0, m - 4); MFMA(m, n, 1, m - 4);                             \
        }                                                                           \
    __builtin_amdgcn_s_setprio(0);                                                  \
    if ((tt) < NT - 1) { VMC(2); }                                                  \
    BAR();                                                                          \
  }

#pragma unroll 1
    for (int tp = 0; tp < NT; tp += 2) {
        DO_TILE(0, tp);
        DO_TILE(1, tp + 1);
    }

    // ---- epilogue: bias + swish + extra bias, GroupNorm per 128-col group ----
    // acc[m][n][j]: row = wm*128 + m*16 + h*4 + j, col = wn*64 + n*16 + r
    const int colbase = bcol * BN + wn * 64;
    float bl[4], be[4], gwv[4], gbv[4];
#pragma unroll
    for (int n = 0; n < 4; ++n) {
        int col = colbase + n * 16 + r;
        bl[n] = bias_lin[col];
        be[n] = bias_extra[col];
        gwv[n] = gn_w[col];
        gbv[n] = gn_b[col];
    }

    float s1[8][4], s2[8][4];
#pragma unroll
    for (int m = 0; m < 8; ++m)
#pragma unroll
        for (int j = 0; j < 4; ++j) { s1[m][j] = 0.f; s2[m][j] = 0.f; }

#pragma unroll
    for (int m = 0; m < 8; ++m)
#pragma unroll
        for (int n = 0; n < 4; ++n)
#pragma unroll
            for (int j = 0; j < 4; ++j) {
                float z = acc[m][n][j] + bl[n];
                float sw = z / (1.f + __expf(-z)) + be[n];
                acc[m][n][j] = sw;
                s1[m][j] += sw;
                s2[m][j] += sw * sw;
            }

#pragma unroll
    for (int mask = 1; mask < 16; mask <<= 1) {
#pragma unroll
        for (int m = 0; m < 8; ++m)
#pragma unroll
            for (int j = 0; j < 4; ++j) {
                s1[m][j] += __shfl_xor(s1[m][j], mask, 16);
                s2[m][j] += __shfl_xor(s2[m][j], mask, 16);
            }
    }

    float* sred = (float*)lds;  // [2 stat][2 group-half][2 wave-pair][256 rows]
    const int gh = wn >> 1;
    const int p = wn & 1;
    if (r == 0) {
#pragma unroll
        for (int m = 0; m < 8; ++m)
#pragma unroll
            for (int j = 0; j < 4; ++j) {
                int row = wm * 128 + m * 16 + h * 4 + j;
                sred[((0 * 2 + gh) * 2 + p) * 256 + row] = s1[m][j];
                sred[((1 * 2 + gh) * 2 + p) * 256 + row] = s2[m][j];
            }
    }
    __syncthreads();

    const size_t orow0 = (size_t)brow * BM;
#pragma unroll
    for (int m = 0; m < 8; ++m)
#pragma unroll
        for (int j = 0; j < 4; ++j) {
            int row = wm * 128 + m * 16 + h * 4 + j;
            float mu = (sred[((0 * 2 + gh) * 2 + 0) * 256 + row] +
                        sred[((0 * 2 + gh) * 2 + 1) * 256 + row]) * (1.f / 128.f);
            float ex2 = (sred[((1 * 2 + gh) * 2 + 0) * 256 + row] +
                         sred[((1 * 2 + gh) * 2 + 1) * 256 + row]) * (1.f / 128.f);
            float var = ex2 - mu * mu;
            float rs = rsqrtf(var + 1e-5f);
            float* orow = out + (orow0 + row) * N_DIM;
#pragma unroll
            for (int n = 0; n < 4; ++n) {
                int col = colbase + n * 16 + r;
                orow[col] = (acc[m][n][j] - mu) * rs * gwv[n] + gbv[n];
            }
        }
}

extern "C" void kernel_launch(void* const* d_in, const int* in_sizes, int n_in,
                              void* d_out, int out_size, void* d_ws, size_t ws_size,
                              hipStream_t stream) {
    const float* x        = (const float*)d_in[0];
    const float* weight   = (const float*)d_in[1];
    const float* bias_lin = (const float*)d_in[2];
    const float* bias_ex  = (const float*)d_in[3];
    const float* gn_w     = (const float*)d_in[4];
    const float* gn_b     = (const float*)d_in[5];
    float* out = (float*)d_out;

    ushort* xb = (ushort*)d_ws;                     // 32 MiB bf16
    ushort* wb = xb + (size_t)M_DIM * K_DIM;        // 16 MiB bf16

    {
        int n8 = (M_DIM * K_DIM) / 8;
        f32_to_bf16_k<<<n8 / 256, 256, 0, stream>>>(x, xb, n8);
    }
    {
        int n8 = (N_DIM * K_DIM) / 8;
        f32_to_bf16_k<<<n8 / 256, 256, 0, stream>>>(weight, wb, n8);
    }

    (void)hipFuncSetAttribute((const void*)gemm_swish_gn,
                              hipFuncAttributeMaxDynamicSharedMemorySize, 131072);

    dim3 grid((M_DIM / BM) * (N_DIM / BN));  // 512 blocks
    gemm_swish_gn<<<grid, 512, 131072, stream>>>(xb, wb, bias_lin, bias_ex, gn_w, gn_b, out);
}

// Round 6
// 186.613 us; speedup vs baseline: 1.3755x; 1.0243x over previous
//
#include <hip/hip_runtime.h>

// Fused: z = x @ W^T + b_lin; y = swish(z) + b_ex; GroupNorm(32 groups) * gn_w + gn_b
// x: [8192, 2048] f32, W: [4096, 2048] f32, out: [8192, 4096] f32
// Round 6: ONE barrier per phase (m201 rhythm). Phase = {reads; stage; gate?;
// BAR; lgkm0; 16 MFMA}. Inter-wave skew across the MFMA cluster provides the
// MFMA || LDS-read overlap. R2-proven 0-conflict LDS geometry kept.

typedef __attribute__((ext_vector_type(8))) short short8;
typedef __attribute__((ext_vector_type(4))) float f32x4;

#define M_DIM 8192
#define N_DIM 4096
#define K_DIM 2048
#define BM 256
#define BN 256
#define BK 64
#define NT (K_DIM / BK)  // 32

#define AS1 __attribute__((address_space(1)))
#define AS3 __attribute__((address_space(3)))

// ---------------- f32 -> bf16 (RNE) convert, 8 elems/thread ----------------
__global__ void f32_to_bf16_k(const float* __restrict__ in, ushort* __restrict__ out, int n8) {
    int i = blockIdx.x * blockDim.x + threadIdx.x;
    if (i >= n8) return;
    const float4* p = (const float4*)in + 2 * (size_t)i;
    float4 a = p[0], b = p[1];
    float v[8] = {a.x, a.y, a.z, a.w, b.x, b.y, b.z, b.w};
    ushort rr[8];
#pragma unroll
    for (int j = 0; j < 8; ++j) {
        unsigned u = __float_as_uint(v[j]);
        rr[j] = (ushort)((u + 0x7fffu + ((u >> 16) & 1u)) >> 16);  // RNE
    }
    uint4 o;
    o.x = (unsigned)rr[0] | ((unsigned)rr[1] << 16);
    o.y = (unsigned)rr[2] | ((unsigned)rr[3] << 16);
    o.z = (unsigned)rr[4] | ((unsigned)rr[5] << 16);
    o.w = (unsigned)rr[6] | ((unsigned)rr[7] << 16);
    ((uint4*)out)[i] = o;
}

// LDS: 2 buffers x 64KB. Buffer (ushort offsets): A [0,16384), B [16384,32768);
// 256 rows x 64 ushorts (128B rows, kk0|kk1 halves in-row).
// Read swizzle: 16B-slot = (kk*4+h) ^ (r&7)  [R2/R5-proven 0-conflict].
// Staged linearly (global_load_lds); global SOURCE col pre-swizzled.

#define BAR() __builtin_amdgcn_s_barrier()
#define LGKM0() do { asm volatile("s_waitcnt lgkmcnt(0)" ::: "memory"); __builtin_amdgcn_sched_barrier(0); } while (0)
#define VMC(n_) do { asm volatile("s_waitcnt vmcnt(" #n_ ")" ::: "memory"); __builtin_amdgcn_sched_barrier(0); } while (0)

__global__ __launch_bounds__(512, 2) void gemm_swish_gn(
    const ushort* __restrict__ xb, const ushort* __restrict__ wb,
    const float* __restrict__ bias_lin, const float* __restrict__ bias_extra,
    const float* __restrict__ gn_w, const float* __restrict__ gn_b,
    float* __restrict__ out)
{
    extern __shared__ __align__(16) ushort lds[];  // 2 x 32768 ushorts

    const int t = threadIdx.x;
    const int w = t >> 6;
    const int l = t & 63;
    const int wm = w >> 2;   // 0..1
    const int wn = w & 3;    // 0..3
    const int h = l >> 4;    // 0..3
    const int r = l & 15;    // 0..15

    // T1: XCD swizzle (512 blocks, bijective)
    const int bid = blockIdx.x;
    const int id = (bid & 7) * 64 + (bid >> 3);
    const int brow = id & 31;   // M tile
    const int bcol = id >> 5;   // N tile (= 2 GroupNorm groups)

    // ---- staging: thread t covers row s=t>>3 (per 64-row round), 16B slot t&7,
    // source col pre-swizzled by slot ^= (row&7).
    const int s = t >> 3;
    const int scol = (((t & 7) ^ (s & 7)) << 3);            // ushorts
    const ushort* pA = xb + (size_t)(brow * BM + s) * K_DIM + scol;
    const int rB = (s & 31) + ((s >> 5) << 6);              // B scattered rows
    const ushort* pB = wb + (size_t)(bcol * BN + rB) * K_DIM + scol;
    const int dstA = t * 8;
    const int dstB = rB * 64 + ((t & 7) << 3);

    // chunk rounds: A-lo ROFF {0,128}; A-hi {64,192}; B-lo {0,128}; B-hi {32,160}
#define STG_A(P, ROFF) __builtin_amdgcn_global_load_lds(                         \
        (const AS1 void*)(pA + (size_t)(ROFF) * K_DIM),                          \
        (AS3 void*)&lds[(P) * 32768 + (ROFF) * 64 + dstA], 16, 0, 0)
#define STG_B(P, ROFF) __builtin_amdgcn_global_load_lds(                         \
        (const AS1 void*)(pB + (size_t)(ROFF) * K_DIM),                          \
        (AS3 void*)&lds[(P) * 32768 + 16384 + (ROFF) * 64 + dstB], 16, 0, 0)

    // fragment read offsets (ushorts): row*64 + ((kk*32 + h*8) ^ (r&7)*8)
    const int xr8 = (r & 7) << 3;
    const int aOff0 = (wm * 128 + r) * 64 + ((h << 3) ^ xr8);
    const int aOff1 = aOff0 ^ 32;
    const int bOff0 = 16384 + (wn * 64 + r) * 64 + ((h << 3) ^ xr8);
    const int bOff1 = bOff0 ^ 32;

    f32x4 acc[8][4];
#pragma unroll
    for (int m = 0; m < 8; ++m)
#pragma unroll
        for (int n = 0; n < 4; ++n)
            acc[m][n] = f32x4{0.f, 0.f, 0.f, 0.f};

    // ---- prologue: stage tile 0 (issue order Alo, Blo, Bhi, Ahi), gate, BAR
    STG_A(0, 0); STG_A(0, 128);   // Alo
    STG_B(0, 0); STG_B(0, 128);   // Blo
    STG_B(0, 32); STG_B(0, 160);  // Bhi
    STG_A(0, 64); STG_A(0, 192);  // Ahi
    pA += BK; pB += BK;
    VMC(4);                        // Alo0, Blo0 landed
    BAR();

    short8 aF[4][2], bF[4][2];

#define MFMA(mm, nn, kk, ai) \
    acc[mm][nn] = __builtin_amdgcn_mfma_f32_16x16x32_bf16(aF[ai][kk], bF[nn][kk], acc[mm][nn], 0, 0, 0)

    // Phase = { reads(this); stage(next tile); gate; BAR; LGKM0; 16 MFMA }.
    // Stage order per tile: ph1 Alo', ph2 Blo'+Bhi', ph3 Ahi'.
    // Gates (gate_p protects reads of phase p+1): ph1 VMC(4), ph2 VMC(6),
    // ph4 VMC(4); tail tile: VMC(2)/VMC(0)/none.
#define DO_TILE(P, tt)                                                              \
  {                                                                                 \
    /* ---- ph1: reads Alo(m0-3)+Blo(n0-1); stage Alo'; MFMA m0-3 x n0-1 ---- */    \
    _Pragma("unroll") for (int m = 0; m < 4; ++m) {                                 \
        aF[m][0] = *(const short8*)&lds[(P) * 32768 + aOff0 + m * 1024];            \
        aF[m][1] = *(const short8*)&lds[(P) * 32768 + aOff1 + m * 1024];            \
    }                                                                               \
    _Pragma("unroll") for (int n = 0; n < 2; ++n) {                                 \
        bF[n][0] = *(const short8*)&lds[(P) * 32768 + bOff0 + n * 1024];            \
        bF[n][1] = *(const short8*)&lds[(P) * 32768 + bOff1 + n * 1024];            \
    }                                                                               \
    if ((tt) != NT - 1) { STG_A((P) ^ 1, 0); STG_A((P) ^ 1, 128); }                 \
    if ((tt) == NT - 1) { VMC(2); } else { VMC(4); }                                \
    BAR(); LGKM0();                                                                 \
    __builtin_amdgcn_s_setprio(1);                                                  \
    _Pragma("unroll") for (int m = 0; m < 4; ++m)                                   \
        _Pragma("unroll") for (int n = 0; n < 2; ++n) {                             \
            MFMA(m, n, 0, m); MFMA(m, n, 1, m);                                     \
        }                                                                           \
    __builtin_amdgcn_s_setprio(0);                                                  \
    /* ---- ph2: reads Bhi(n2-3); stage Blo'+Bhi'; MFMA m0-3 x n2-3 ---- */         \
    _Pragma("unroll") for (int n = 2; n < 4; ++n) {                                 \
        bF[n][0] = *(const short8*)&lds[(P) * 32768 + bOff0 + n * 1024];            \
        bF[n][1] = *(const short8*)&lds[(P) * 32768 + bOff1 + n * 1024];            \
    }                                                                               \
    if ((tt) != NT - 1) { STG_B((P) ^ 1, 0); STG_B((P) ^ 1, 128);                   \
                          STG_B((P) ^ 1, 32); STG_B((P) ^ 1, 160); }                \
    if ((tt) == NT - 1) { VMC(0); } else { VMC(6); }                                \
    BAR(); LGKM0();                                                                 \
    __builtin_amdgcn_s_setprio(1);                                                  \
    _Pragma("unroll") for (int m = 0; m < 4; ++m)                                   \
        _Pragma("unroll") for (int n = 2; n < 4; ++n) {                             \
            MFMA(m, n, 0, m); MFMA(m, n, 1, m);                                     \
        }                                                                           \
    __builtin_amdgcn_s_setprio(0);                                                  \
    /* ---- ph3: reads Ahi(m4-7); stage Ahi'; MFMA m4-7 x n0-1 ---- */              \
    _Pragma("unroll") for (int m = 4; m < 8; ++m) {                                 \
        aF[m - 4][0] = *(const short8*)&lds[(P) * 32768 + aOff0 + m * 1024];        \
        aF[m - 4][1] = *(const short8*)&lds[(P) * 32768 + aOff1 + m * 1024];        \
    }                                                                               \
    if ((tt) != NT - 1) { STG_A((P) ^ 1, 64); STG_A((P) ^ 1, 192);                  \
                          pA += BK; pB += BK; }                                     \
    BAR(); LGKM0();                                                                 \
    __builtin_amdgcn_s_setprio(1);                                                  \
    _Pragma("unroll") for (int m = 4; m < 8; ++m)                                   \
        _Pragma("unroll") for (int n = 0; n < 2; ++n) {                             \
            MFMA(m, n, 0, m - 4); MFMA(m, n, 1, m - 4);                             \
        }                                                                           \
    __builtin_amdgcn_s_setprio(0);                                                  \
    /* ---- ph4: register-only; gate for next tile's ph1 ---- */                    \
    if ((tt) < NT - 1) { VMC(4); }                                                  \
    BAR();                                                                          \
    __builtin_amdgcn_s_setprio(1);                                                  \
    _Pragma("unroll") for (int m = 4; m < 8; ++m)                                   \
        _Pragma("unroll") for (int n = 2; n < 4; ++n) {                             \
            MFMA(m, n, 0, m - 4); MFMA(m, n, 1, m - 4);                             \
        }                                                                           \
    __builtin_amdgcn_s_setprio(0);                                                  \
  }

#pragma unroll 1
    for (int tp = 0; tp < NT; tp += 2) {
        DO_TILE(0, tp);
        DO_TILE(1, tp + 1);
    }

    // ---- epilogue: bias + swish + extra bias, GroupNorm per 128-col group ----
    // acc[m][n][j]: row = wm*128 + m*16 + h*4 + j, col = wn*64 + n*16 + r
    const int colbase = bcol * BN + wn * 64;
    float bl[4], be[4], gwv[4], gbv[4];
#pragma unroll
    for (int n = 0; n < 4; ++n) {
        int col = colbase + n * 16 + r;
        bl[n] = bias_lin[col];
        be[n] = bias_extra[col];
        gwv[n] = gn_w[col];
        gbv[n] = gn_b[col];
    }

    float s1[8][4], s2[8][4];
#pragma unroll
    for (int m = 0; m < 8; ++m)
#pragma unroll
        for (int j = 0; j < 4; ++j) { s1[m][j] = 0.f; s2[m][j] = 0.f; }

#pragma unroll
    for (int m = 0; m < 8; ++m)
#pragma unroll
        for (int n = 0; n < 4; ++n)
#pragma unroll
            for (int j = 0; j < 4; ++j) {
                float z = acc[m][n][j] + bl[n];
                float sw = z / (1.f + __expf(-z)) + be[n];
                acc[m][n][j] = sw;
                s1[m][j] += sw;
                s2[m][j] += sw * sw;
            }

#pragma unroll
    for (int mask = 1; mask < 16; mask <<= 1) {
#pragma unroll
        for (int m = 0; m < 8; ++m)
#pragma unroll
            for (int j = 0; j < 4; ++j) {
                s1[m][j] += __shfl_xor(s1[m][j], mask, 16);
                s2[m][j] += __shfl_xor(s2[m][j], mask, 16);
            }
    }

    __syncthreads();  // all LDS tile reads done before aliasing as stats
    float* sred = (float*)lds;  // [2 stat][2 group-half][2 wave-pair][256 rows]
    const int gh = wn >> 1;
    const int p = wn & 1;
    if (r == 0) {
#pragma unroll
        for (int m = 0; m < 8; ++m)
#pragma unroll
            for (int j = 0; j < 4; ++j) {
                int row = wm * 128 + m * 16 + h * 4 + j;
                sred[((0 * 2 + gh) * 2 + p) * 256 + row] = s1[m][j];
                sred[((1 * 2 + gh) * 2 + p) * 256 + row] = s2[m][j];
            }
    }
    __syncthreads();

    const size_t orow0 = (size_t)brow * BM;
#pragma unroll
    for (int m = 0; m < 8; ++m)
#pragma unroll
        for (int j = 0; j < 4; ++j) {
            int row = wm * 128 + m * 16 + h * 4 + j;
            float mu = (sred[((0 * 2 + gh) * 2 + 0) * 256 + row] +
                        sred[((0 * 2 + gh) * 2 + 1) * 256 + row]) * (1.f / 128.f);
            float ex2 = (sred[((1 * 2 + gh) * 2 + 0) * 256 + row] +
                         sred[((1 * 2 + gh) * 2 + 1) * 256 + row]) * (1.f / 128.f);
            float var = ex2 - mu * mu;
            float rs = rsqrtf(var + 1e-5f);
            float* orow = out + (orow0 + row) * N_DIM;
#pragma unroll
            for (int n = 0; n < 4; ++n) {
                int col = colbase + n * 16 + r;
                orow[col] = (acc[m][n][j] - mu) * rs * gwv[n] + gbv[n];
            }
        }
}

extern "C" void kernel_launch(void* const* d_in, const int* in_sizes, int n_in,
                              void* d_out, int out_size, void* d_ws, size_t ws_size,
                              hipStream_t stream) {
    const float* x        = (const float*)d_in[0];
    const float* weight   = (const float*)d_in[1];
    const float* bias_lin = (const float*)d_in[2];
    const float* bias_ex  = (const float*)d_in[3];
    const float* gn_w     = (const float*)d_in[4];
    const float* gn_b     = (const float*)d_in[5];
    float* out = (float*)d_out;

    ushort* xb = (ushort*)d_ws;                     // 32 MiB bf16
    ushort* wb = xb + (size_t)M_DIM * K_DIM;        // 16 MiB bf16

    {
        int n8 = (M_DIM * K_DIM) / 8;
        f32_to_bf16_k<<<n8 / 256, 256, 0, stream>>>(x, xb, n8);
    }
    {
        int n8 = (N_DIM * K_DIM) / 8;
        f32_to_bf16_k<<<n8 / 256, 256, 0, stream>>>(weight, wb, n8);
    }

    (void)hipFuncSetAttribute((const void*)gemm_swish_gn,
                              hipFuncAttributeMaxDynamicSharedMemorySize, 131072);

    dim3 grid((M_DIM / BM) * (N_DIM / BN));  // 512 blocks
    gemm_swish_gn<<<grid, 512, 131072, stream>>>(xb, wb, bias_lin, bias_ex, gn_w, gn_b, out);
}